// Round 1
// baseline (1188.216 us; speedup 1.0000x reference)
//
#include <hip/hip_runtime.h>
#include <stdint.h>
#include <stddef.h>

// ---------- types ----------
typedef __bf16 bf16x8 __attribute__((ext_vector_type(8)));
typedef float  f32x4  __attribute__((ext_vector_type(4)));

// float -> bf16 bits, round-to-nearest-even (finite inputs)
__device__ __forceinline__ unsigned short f2bf(float f) {
  unsigned int u = __builtin_bit_cast(unsigned int, f);
  u += 0x7fffu + ((u >> 16) & 1u);
  return (unsigned short)(u >> 16);
}

__device__ __forceinline__ void gld_lds16(const void* g, void* l) {
  __builtin_amdgcn_global_load_lds(
      (__attribute__((address_space(1))) void*)(g),
      (__attribute__((address_space(3))) void*)(l), 16, 0, 0);
}

// ---------- kernel 1: quotient-remainder fake-quant of x, emit bf16 ----------
// one wave per 128-element group; 2 elements / lane
__global__ __launch_bounds__(256) void quant_x_kernel(
    const float* __restrict__ x, unsigned short* __restrict__ xb, long long ngroups)
{
  const int lane = threadIdx.x & 63;
  const int wv   = threadIdx.x >> 6;
  long long g = (long long)blockIdx.x * 4 + wv;
  if (g >= ngroups) return;

  const float* xg = x + g * 128;
  float2 v = *reinterpret_cast<const float2*>(xg + lane * 2);

  // group max |x|
  float m = fmaxf(fabsf(v.x), fabsf(v.y));
  #pragma unroll
  for (int off = 32; off; off >>= 1) m = fmaxf(m, __shfl_xor(m, off));
  m = fmaxf(m, 1e-8f);

  float t = m / 7.0f;
  float base = t <= 2.f ? 2.f : t <= 4.f ? 4.f : t <= 8.f ? 8.f
             : t <= 16.f ? 16.f : t <= 32.f ? 32.f : 64.f;
  float inv_base = 1.0f / base;  // exact (power of 2)

  float q0 = fminf(fmaxf(rintf(v.x * inv_base), -7.f), 7.f);
  float q1 = fminf(fmaxf(rintf(v.y * inv_base), -7.f), 7.f);
  float r0 = v.x - base * q0;
  float r1 = v.y - base * q1;

  // group max |r|
  float mr = fmaxf(fabsf(r0), fabsf(r1));
  #pragma unroll
  for (int off = 32; off; off >>= 1) mr = fmaxf(mr, __shfl_xor(mr, off));
  mr = fmaxf(mr, 1e-8f);
  float scale_r = mr / 7.0f;

  float rd0 = fminf(fmaxf(rintf(r0 / scale_r), -8.f), 7.f) * scale_r;
  float rd1 = fminf(fmaxf(rintf(r1 / scale_r), -8.f), 7.f) * scale_r;

  float y0 = base * q0 + rd0;
  float y1 = base * q1 + rd1;

  unsigned int packed = (unsigned int)f2bf(y0) | ((unsigned int)f2bf(y1) << 16);
  *reinterpret_cast<unsigned int*>(xb + g * 128 + lane * 2) = packed;
}

// ---------- kernel 2: fp32 -> bf16 weight conversion ----------
__global__ __launch_bounds__(256) void cvt_w_kernel(
    const float* __restrict__ w, unsigned short* __restrict__ wb, long long n)
{
  long long i = ((long long)blockIdx.x * blockDim.x + threadIdx.x) * 8;
  if (i + 7 >= n) {
    if (i >= n) return;
    for (long long j = i; j < n; ++j) wb[j] = f2bf(w[j]);
    return;
  }
  float4 v0 = *reinterpret_cast<const float4*>(w + i);
  float4 v1 = *reinterpret_cast<const float4*>(w + i + 4);
  uint4 o;
  o.x = (unsigned)f2bf(v0.x) | ((unsigned)f2bf(v0.y) << 16);
  o.y = (unsigned)f2bf(v0.z) | ((unsigned)f2bf(v0.w) << 16);
  o.z = (unsigned)f2bf(v1.x) | ((unsigned)f2bf(v1.y) << 16);
  o.w = (unsigned)f2bf(v1.z) | ((unsigned)f2bf(v1.w) << 16);
  *reinterpret_cast<uint4*>(wb + i) = o;
}

// ---------- kernel 3: bf16 NT-GEMM (A[M][K] * B[N][K]^T) + bias, fp32 out ----------
#define BM 128
#define BN 128
#define BK 64

__global__ __launch_bounds__(256) void gemm_bt_bias(
    const unsigned short* __restrict__ A,   // [M][K] bf16 bits
    const unsigned short* __restrict__ B,   // [N][K] bf16 bits
    const float* __restrict__ bias,         // [N]
    float* __restrict__ C,                  // [M][N] fp32
    int M, int N, int K)
{
  __shared__ unsigned short As[BM * BK];   // 16 KB
  __shared__ unsigned short Bs[BN * BK];   // 16 KB

  const int tid  = threadIdx.x;
  const int lane = tid & 63;
  const int wv   = tid >> 6;       // 0..3
  const int wr   = wv >> 1;        // wave row (0..1)
  const int wc   = wv & 1;         // wave col (0..1)

  // bijective XCD swizzle (grid % 8 == 0 for this shape)
  int nwg = gridDim.x;
  int bid = blockIdx.x;
  int wg = ((nwg & 7) == 0) ? ((bid & 7) * (nwg >> 3) + (bid >> 3)) : bid;

  const int ntn = N / BN;
  const int tm = wg / ntn;
  const int tn = wg % ntn;
  const size_t m0 = (size_t)tm * BM;
  const size_t n0 = (size_t)tn * BN;

  f32x4 acc[4][4];
  #pragma unroll
  for (int i = 0; i < 4; i++)
    #pragma unroll
    for (int j = 0; j < 4; j++)
      acc[i][j] = (f32x4){0.f, 0.f, 0.f, 0.f};

  const int laneq = lane & 15;     // fragment row/col
  const int laneh = lane >> 4;     // k-group 0..3

  for (int k0 = 0; k0 < K; k0 += BK) {
    // ---- stage A,B tiles into LDS (global_load_lds, 16B/lane) ----
    #pragma unroll
    for (int c = 0; c < 4; c++) {
      int ch  = c * 256 + tid;       // 0..1023
      int row = ch >> 3;             // 0..127
      int kc  = (ch & 7) * 8;        // 0..56
      const unsigned short* ga = A + (m0 + row) * (size_t)K + k0 + kc;
      const unsigned short* gb = B + (n0 + row) * (size_t)K + k0 + kc;
      gld_lds16(ga, (char*)As + (c * 256 + wv * 64) * 16);
      gld_lds16(gb, (char*)Bs + (c * 256 + wv * 64) * 16);
    }
    __syncthreads();   // compiler inserts vmcnt(0) drain

    // ---- compute: 2 k-substeps of 32, 4x4 fragments of 16x16 ----
    #pragma unroll
    for (int ks = 0; ks < 2; ks++) {
      bf16x8 af[4], bfr[4];
      const int kk = ks * 32 + laneh * 8;
      #pragma unroll
      for (int i = 0; i < 4; i++) {
        int ra = wr * 64 + i * 16 + laneq;
        int rb = wc * 64 + i * 16 + laneq;
        af[i]  = *reinterpret_cast<const bf16x8*>(&As[ra * BK + kk]);
        bfr[i] = *reinterpret_cast<const bf16x8*>(&Bs[rb * BK + kk]);
      }
      #pragma unroll
      for (int i = 0; i < 4; i++)
        #pragma unroll
        for (int j = 0; j < 4; j++)
          acc[i][j] = __builtin_amdgcn_mfma_f32_16x16x32_bf16(af[i], bfr[j], acc[i][j], 0, 0, 0);
    }
    __syncthreads();
  }

  // ---- epilogue: C = acc + bias ----
  // C/D layout: col = lane&15, row = (lane>>4)*4 + reg
  #pragma unroll
  for (int j = 0; j < 4; j++) {
    int col = (int)n0 + wc * 64 + j * 16 + laneq;
    float bv = bias[col];
    #pragma unroll
    for (int i = 0; i < 4; i++) {
      int row = (int)m0 + wr * 64 + i * 16 + laneh * 4;
      float* cp = C + (size_t)row * N + col;
      #pragma unroll
      for (int t = 0; t < 4; t++)
        cp[(size_t)t * N] = acc[i][j][t] + bv;
    }
  }
}

// ---------- launcher ----------
extern "C" void kernel_launch(void* const* d_in, const int* in_sizes, int n_in,
                              void* d_out, int out_size, void* d_ws, size_t ws_size,
                              hipStream_t stream) {
  const float* x    = (const float*)d_in[0];
  const float* w    = (const float*)d_in[1];
  const float* bias = (const float*)d_in[2];
  float* out = (float*)d_out;

  const long long xN = in_sizes[0];          // M*K
  const long long wN = in_sizes[1];          // N*K
  const int N = in_sizes[2];
  const int K = (int)(wN / N);
  const int M = (int)(xN / K);

  unsigned short* xb = (unsigned short*)d_ws;          // M*K bf16
  unsigned short* wb = xb + xN;                        // N*K bf16

  // 1) fake-quant x -> bf16
  long long ngroups = xN / 128;
  long long qblocks = (ngroups + 3) / 4;
  quant_x_kernel<<<(int)qblocks, 256, 0, stream>>>(x, xb, ngroups);

  // 2) weight fp32 -> bf16
  long long cblocks = (wN + 2047) / 2048;
  cvt_w_kernel<<<(int)cblocks, 256, 0, stream>>>(w, wb, wN);

  // 3) GEMM + bias
  int grid = (M / BM) * (N / BN);
  gemm_bt_bias<<<grid, 256, 0, stream>>>(xb, wb, bias, out, M, N, K);
}

// Round 2
// 1126.426 us; speedup vs baseline: 1.0549x; 1.0549x over previous
//
#include <hip/hip_runtime.h>
#include <stdint.h>
#include <stddef.h>

// ---------- types ----------
typedef __bf16 bf16x8 __attribute__((ext_vector_type(8)));
typedef float  f32x4  __attribute__((ext_vector_type(4)));

// float -> bf16 bits, round-to-nearest-even (finite inputs)
__device__ __forceinline__ unsigned short f2bf(float f) {
  unsigned int u = __builtin_bit_cast(unsigned int, f);
  u += 0x7fffu + ((u >> 16) & 1u);
  return (unsigned short)(u >> 16);
}

__device__ __forceinline__ void gld_lds16(const void* g, void* l) {
  __builtin_amdgcn_global_load_lds(
      (__attribute__((address_space(1))) void*)(g),
      (__attribute__((address_space(3))) void*)(l), 16, 0, 0);
}

// ---------- kernel 1: quotient-remainder fake-quant of x, emit bf16 ----------
// one wave per 128-element group; 2 elements / lane
__global__ __launch_bounds__(256) void quant_x_kernel(
    const float* __restrict__ x, unsigned short* __restrict__ xb, long long ngroups)
{
  const int lane = threadIdx.x & 63;
  const int wv   = threadIdx.x >> 6;
  long long g = (long long)blockIdx.x * 4 + wv;
  if (g >= ngroups) return;

  const float* xg = x + g * 128;
  float2 v = *reinterpret_cast<const float2*>(xg + lane * 2);

  // group max |x|
  float m = fmaxf(fabsf(v.x), fabsf(v.y));
  #pragma unroll
  for (int off = 32; off; off >>= 1) m = fmaxf(m, __shfl_xor(m, off));
  m = fmaxf(m, 1e-8f);

  float t = m / 7.0f;
  float base = t <= 2.f ? 2.f : t <= 4.f ? 4.f : t <= 8.f ? 8.f
             : t <= 16.f ? 16.f : t <= 32.f ? 32.f : 64.f;
  float inv_base = 1.0f / base;  // exact (power of 2)

  float q0 = fminf(fmaxf(rintf(v.x * inv_base), -7.f), 7.f);
  float q1 = fminf(fmaxf(rintf(v.y * inv_base), -7.f), 7.f);
  float r0 = v.x - base * q0;
  float r1 = v.y - base * q1;

  // group max |r|
  float mr = fmaxf(fabsf(r0), fabsf(r1));
  #pragma unroll
  for (int off = 32; off; off >>= 1) mr = fmaxf(mr, __shfl_xor(mr, off));
  mr = fmaxf(mr, 1e-8f);
  float scale_r = mr / 7.0f;

  float rd0 = fminf(fmaxf(rintf(r0 / scale_r), -8.f), 7.f) * scale_r;
  float rd1 = fminf(fmaxf(rintf(r1 / scale_r), -8.f), 7.f) * scale_r;

  float y0 = base * q0 + rd0;
  float y1 = base * q1 + rd1;

  unsigned int packed = (unsigned int)f2bf(y0) | ((unsigned int)f2bf(y1) << 16);
  *reinterpret_cast<unsigned int*>(xb + g * 128 + lane * 2) = packed;
}

// ---------- kernel 2: fp32 -> bf16 weight conversion ----------
__global__ __launch_bounds__(256) void cvt_w_kernel(
    const float* __restrict__ w, unsigned short* __restrict__ wb, long long n)
{
  long long i = ((long long)blockIdx.x * blockDim.x + threadIdx.x) * 8;
  if (i + 7 >= n) {
    if (i >= n) return;
    for (long long j = i; j < n; ++j) wb[j] = f2bf(w[j]);
    return;
  }
  float4 v0 = *reinterpret_cast<const float4*>(w + i);
  float4 v1 = *reinterpret_cast<const float4*>(w + i + 4);
  uint4 o;
  o.x = (unsigned)f2bf(v0.x) | ((unsigned)f2bf(v0.y) << 16);
  o.y = (unsigned)f2bf(v0.z) | ((unsigned)f2bf(v0.w) << 16);
  o.z = (unsigned)f2bf(v1.x) | ((unsigned)f2bf(v1.y) << 16);
  o.w = (unsigned)f2bf(v1.z) | ((unsigned)f2bf(v1.w) << 16);
  *reinterpret_cast<uint4*>(wb + i) = o;
}

// ---------- kernel 3: bf16 NT-GEMM (A[M][K] * B[N][K]^T) + bias, fp32 out ----------
// LDS tiles [128][64] bf16 with T2 XOR-swizzle: the 16B slot index within each
// 128B row is XORed with (row&7).  global_load_lds writes LINEARLY, so the
// swizzle is applied by inverse-permuting the GLOBAL source address (rule #21)
// and XORing the ds_read address at compute time.
#define BM 128
#define BN 128
#define BK 64

__global__ __launch_bounds__(256) void gemm_bt_bias(
    const unsigned short* __restrict__ A,   // [M][K] bf16 bits
    const unsigned short* __restrict__ B,   // [N][K] bf16 bits
    const float* __restrict__ bias,         // [N]
    float* __restrict__ C,                  // [M][N] fp32
    int M, int N, int K)
{
  __shared__ unsigned short As[BM * BK];   // 16 KB
  __shared__ unsigned short Bs[BN * BK];   // 16 KB

  const int tid  = threadIdx.x;
  const int lane = tid & 63;
  const int wv   = tid >> 6;       // 0..3
  const int wr   = wv >> 1;        // wave row (0..1)
  const int wc   = wv & 1;         // wave col (0..1)

  // bijective XCD swizzle (grid % 8 == 0 for this shape)
  int nwg = gridDim.x;
  int bid = blockIdx.x;
  int wg = ((nwg & 7) == 0) ? ((bid & 7) * (nwg >> 3) + (bid >> 3)) : bid;

  const int ntn = N / BN;
  const int tm = wg / ntn;
  const int tn = wg % ntn;
  const size_t m0 = (size_t)tm * BM;
  const size_t n0 = (size_t)tn * BN;

  f32x4 acc[4][4];
  #pragma unroll
  for (int i = 0; i < 4; i++)
    #pragma unroll
    for (int j = 0; j < 4; j++)
      acc[i][j] = (f32x4){0.f, 0.f, 0.f, 0.f};

  const int laneq = lane & 15;     // fragment row/col
  const int laneh = lane >> 4;     // k-group 0..3
  const int lq7   = laneq & 7;     // row&7 for all fragment reads (16|i*16)

  for (int k0 = 0; k0 < K; k0 += BK) {
    // ---- stage A,B tiles into LDS (global_load_lds, 16B/lane) ----
    // LDS chunk ci (16B) holds global slot (ci&7) ^ ((ci>>3)&7) of row ci>>3.
    #pragma unroll
    for (int c = 0; c < 4; c++) {
      int ch  = c * 256 + tid;           // 0..1023 : chunk index
      int row = ch >> 3;                 // 0..127
      int s   = (ch & 7) ^ (row & 7);    // inverse-swizzled global slot
      const unsigned short* ga = A + (m0 + row) * (size_t)K + k0 + s * 8;
      const unsigned short* gb = B + (n0 + row) * (size_t)K + k0 + s * 8;
      gld_lds16(ga, (char*)As + (c * 256 + wv * 64) * 16);
      gld_lds16(gb, (char*)Bs + (c * 256 + wv * 64) * 16);
    }
    __syncthreads();   // compiler inserts vmcnt(0) drain

    // ---- compute: 2 k-substeps of 32, 4x4 fragments of 16x16 ----
    #pragma unroll
    for (int ks = 0; ks < 2; ks++) {
      bf16x8 af[4], bfr[4];
      const int slot = ks * 4 + laneh;          // 16B slot within the row
      const int kswz = (slot ^ lq7) * 8;        // swizzled element offset
      #pragma unroll
      for (int i = 0; i < 4; i++) {
        int ra = wr * 64 + i * 16 + laneq;
        int rb = wc * 64 + i * 16 + laneq;
        af[i]  = *reinterpret_cast<const bf16x8*>(&As[ra * BK + kswz]);
        bfr[i] = *reinterpret_cast<const bf16x8*>(&Bs[rb * BK + kswz]);
      }
      #pragma unroll
      for (int i = 0; i < 4; i++)
        #pragma unroll
        for (int j = 0; j < 4; j++)
          acc[i][j] = __builtin_amdgcn_mfma_f32_16x16x32_bf16(af[i], bfr[j], acc[i][j], 0, 0, 0);
    }
    __syncthreads();
  }

  // ---- epilogue: C = acc + bias ----
  // C/D layout: col = lane&15, row = (lane>>4)*4 + reg
  #pragma unroll
  for (int j = 0; j < 4; j++) {
    int col = (int)n0 + wc * 64 + j * 16 + laneq;
    float bv = bias[col];
    #pragma unroll
    for (int i = 0; i < 4; i++) {
      int row = (int)m0 + wr * 64 + i * 16 + laneh * 4;
      float* cp = C + (size_t)row * N + col;
      #pragma unroll
      for (int t = 0; t < 4; t++)
        cp[(size_t)t * N] = acc[i][j][t] + bv;
    }
  }
}

// ---------- launcher ----------
extern "C" void kernel_launch(void* const* d_in, const int* in_sizes, int n_in,
                              void* d_out, int out_size, void* d_ws, size_t ws_size,
                              hipStream_t stream) {
  const float* x    = (const float*)d_in[0];
  const float* w    = (const float*)d_in[1];
  const float* bias = (const float*)d_in[2];
  float* out = (float*)d_out;

  const long long xN = in_sizes[0];          // M*K
  const long long wN = in_sizes[1];          // N*K
  const int N = in_sizes[2];
  const int K = (int)(wN / N);
  const int M = (int)(xN / K);

  unsigned short* xb = (unsigned short*)d_ws;          // M*K bf16
  unsigned short* wb = xb + xN;                        // N*K bf16

  // 1) fake-quant x -> bf16
  long long ngroups = xN / 128;
  long long qblocks = (ngroups + 3) / 4;
  quant_x_kernel<<<(int)qblocks, 256, 0, stream>>>(x, xb, ngroups);

  // 2) weight fp32 -> bf16
  long long cblocks = (wN + 2047) / 2048;
  cvt_w_kernel<<<(int)cblocks, 256, 0, stream>>>(w, wb, wN);

  // 3) GEMM + bias
  int grid = (M / BM) * (N / BN);
  gemm_bt_bias<<<grid, 256, 0, stream>>>(xb, wb, bias, out, M, N, K);
}

// Round 3
// 839.237 us; speedup vs baseline: 1.4158x; 1.3422x over previous
//
#include <hip/hip_runtime.h>
#include <stdint.h>
#include <stddef.h>

// ---------- types ----------
typedef __bf16 bf16x8 __attribute__((ext_vector_type(8)));
typedef float  f32x4  __attribute__((ext_vector_type(4)));

// float -> bf16 bits, round-to-nearest-even (finite inputs)
__device__ __forceinline__ unsigned short f2bf(float f) {
  unsigned int u = __builtin_bit_cast(unsigned int, f);
  u += 0x7fffu + ((u >> 16) & 1u);
  return (unsigned short)(u >> 16);
}

__device__ __forceinline__ void gld_lds16(const void* g, void* l) {
  __builtin_amdgcn_global_load_lds(
      (__attribute__((address_space(1))) void*)(g),
      (__attribute__((address_space(3))) void*)(l), 16, 0, 0);
}

#define BAR()     asm volatile("s_barrier" ::: "memory")
#define WAITVM(n) asm volatile("s_waitcnt vmcnt(" #n ")" ::: "memory")

// ---------- kernel 1: quotient-remainder fake-quant of x, emit bf16 ----------
__global__ __launch_bounds__(256) void quant_x_kernel(
    const float* __restrict__ x, unsigned short* __restrict__ xb, long long ngroups)
{
  const int lane = threadIdx.x & 63;
  const int wv   = threadIdx.x >> 6;
  long long g = (long long)blockIdx.x * 4 + wv;
  if (g >= ngroups) return;

  const float* xg = x + g * 128;
  float2 v = *reinterpret_cast<const float2*>(xg + lane * 2);

  float m = fmaxf(fabsf(v.x), fabsf(v.y));
  #pragma unroll
  for (int off = 32; off; off >>= 1) m = fmaxf(m, __shfl_xor(m, off));
  m = fmaxf(m, 1e-8f);

  float t = m / 7.0f;
  float base = t <= 2.f ? 2.f : t <= 4.f ? 4.f : t <= 8.f ? 8.f
             : t <= 16.f ? 16.f : t <= 32.f ? 32.f : 64.f;
  float inv_base = 1.0f / base;

  float q0 = fminf(fmaxf(rintf(v.x * inv_base), -7.f), 7.f);
  float q1 = fminf(fmaxf(rintf(v.y * inv_base), -7.f), 7.f);
  float r0 = v.x - base * q0;
  float r1 = v.y - base * q1;

  float mr = fmaxf(fabsf(r0), fabsf(r1));
  #pragma unroll
  for (int off = 32; off; off >>= 1) mr = fmaxf(mr, __shfl_xor(mr, off));
  mr = fmaxf(mr, 1e-8f);
  float scale_r = mr / 7.0f;

  float rd0 = fminf(fmaxf(rintf(r0 / scale_r), -8.f), 7.f) * scale_r;
  float rd1 = fminf(fmaxf(rintf(r1 / scale_r), -8.f), 7.f) * scale_r;

  float y0 = base * q0 + rd0;
  float y1 = base * q1 + rd1;

  unsigned int packed = (unsigned int)f2bf(y0) | ((unsigned int)f2bf(y1) << 16);
  *reinterpret_cast<unsigned int*>(xb + g * 128 + lane * 2) = packed;
}

// ---------- kernel 2: fp32 -> bf16 weight conversion ----------
__global__ __launch_bounds__(256) void cvt_w_kernel(
    const float* __restrict__ w, unsigned short* __restrict__ wb, long long n)
{
  long long i = ((long long)blockIdx.x * blockDim.x + threadIdx.x) * 8;
  if (i + 7 >= n) {
    if (i >= n) return;
    for (long long j = i; j < n; ++j) wb[j] = f2bf(w[j]);
    return;
  }
  float4 v0 = *reinterpret_cast<const float4*>(w + i);
  float4 v1 = *reinterpret_cast<const float4*>(w + i + 4);
  uint4 o;
  o.x = (unsigned)f2bf(v0.x) | ((unsigned)f2bf(v0.y) << 16);
  o.y = (unsigned)f2bf(v0.z) | ((unsigned)f2bf(v0.w) << 16);
  o.z = (unsigned)f2bf(v1.x) | ((unsigned)f2bf(v1.y) << 16);
  o.w = (unsigned)f2bf(v1.z) | ((unsigned)f2bf(v1.w) << 16);
  *reinterpret_cast<uint4*>(wb + i) = o;
}

// ---------- kernel 3: 256x256-tile 8-phase bf16 NT-GEMM + bias ----------
// 8 waves (2M x 4N), BK=64, LDS ring = [dbuf][mat][half][128x64] (128 KiB).
// Counted vmcnt(4) at K-tile boundaries; vmcnt(0) only at t==NT-2.
// Stage schedule (1 half-tile / phase), derived from region deaths:
//   p1: A(t+1).h0   (slot dead since t-1's p3 barrier)
//   p2: A(t+1).h1
//   p3: B(t+2).h0   (B(t) dead after this tile's p2 barrier)
//   p4: B(t+2).h1
#define BM 256
#define BN 256
#define BK 64

#define MFMA16(a, b, c) __builtin_amdgcn_mfma_f32_16x16x32_bf16(a, b, c, 0, 0, 0)

__global__ __launch_bounds__(512, 2) void gemm256_bias(
    const unsigned short* __restrict__ A,   // [M][K] bf16 bits
    const unsigned short* __restrict__ B,   // [N][K] bf16 bits
    const float* __restrict__ bias,         // [N]
    float* __restrict__ C,                  // [M][N] fp32
    int M, int N, int K)
{
  __shared__ unsigned short lds[2][2][2][128 * 64];   // [dbuf][A/B][half] : 128 KiB

  const int tid  = threadIdx.x;
  const int lane = tid & 63;
  const int wid  = tid >> 6;       // 0..7
  const int wm   = wid >> 2;       // 0..1
  const int wn   = wid & 3;        // 0..3
  const int laneq = lane & 15;
  const int laneh = lane >> 4;
  const int lq7   = laneq & 7;

  // bijective XCD swizzle (grid % 8 == 0 for this shape)
  int nwg = gridDim.x;
  int bid = blockIdx.x;
  int wg = ((nwg & 7) == 0) ? ((bid & 7) * (nwg >> 3) + (bid >> 3)) : bid;

  const int ntn = N / BN;
  const int tm = wg / ntn;
  const int tn = wg % ntn;
  const size_t m0 = (size_t)tm * BM;
  const size_t n0 = (size_t)tn * BN;

  const int NT = K / BK;

  // swizzled 16B-slot offsets (elements) for ks=0,1
  const int s0 = ((0 * 4 + laneh) ^ lq7) * 8;
  const int s1 = ((1 * 4 + laneh) ^ lq7) * 8;

  f32x4 acc[8][4];
  #pragma unroll
  for (int i = 0; i < 8; i++)
    #pragma unroll
    for (int j = 0; j < 4; j++)
      acc[i][j] = (f32x4){0.f, 0.f, 0.f, 0.f};

  // stage one 128x64 half-tile (2 x global_load_lds per thread)
  auto stage = [&](int mat, int d, int h, int kt) {
    const unsigned short* gbase = (mat == 0)
        ? (A + (m0 + (size_t)h * 128) * (size_t)K)
        : (B + (n0 + (size_t)h * 128) * (size_t)K);
    const int k0 = kt * BK;
    #pragma unroll
    for (int l = 0; l < 2; ++l) {
      int c   = l * 512 + tid;          // chunk 0..1023
      int row = c >> 3;                 // 0..127
      int s   = (c & 7) ^ (row & 7);    // inverse-swizzled global slot
      gld_lds16(gbase + (size_t)row * K + k0 + s * 8,
                (char*)&lds[d][mat][h][0] + (l * 512 + wid * 64) * 16);
    }
  };

  // ---- prologue: tile0 complete + tile1's B halves ----
  stage(0, 0, 0, 0); stage(0, 0, 1, 0);
  stage(1, 0, 0, 0); stage(1, 0, 1, 0);
  stage(1, 1, 0, 1); stage(1, 1, 1, 1);
  WAITVM(4);          // tile0's 8 loads (oldest) arrived
  BAR();

  for (int t = 0; t < NT; ++t) {
    const int d = t & 1;
    const unsigned short* As_ = &lds[d][0][wm][0];
    const unsigned short* Bs_ = &lds[d][1][wn >> 1][0];
    const int brow = (wn & 1) * 64;

    bf16x8 af[4][2], bl[2][2], bh[2][2];

    // ---------- phase 1: read A-lo + B-lo ; stage A(t+1).h0 ----------
    #pragma unroll
    for (int mi = 0; mi < 4; ++mi) {
      af[mi][0] = *(const bf16x8*)&As_[(mi * 16 + laneq) * 64 + s0];
      af[mi][1] = *(const bf16x8*)&As_[(mi * 16 + laneq) * 64 + s1];
    }
    #pragma unroll
    for (int nj = 0; nj < 2; ++nj) {
      bl[nj][0] = *(const bf16x8*)&Bs_[(brow + nj * 16 + laneq) * 64 + s0];
      bl[nj][1] = *(const bf16x8*)&Bs_[(brow + nj * 16 + laneq) * 64 + s1];
    }
    if (t + 1 < NT) stage(0, (t + 1) & 1, 0, t + 1);
    BAR();
    __builtin_amdgcn_s_setprio(1);
    #pragma unroll
    for (int mi = 0; mi < 4; ++mi)
      #pragma unroll
      for (int nj = 0; nj < 2; ++nj) {
        acc[mi][nj] = MFMA16(af[mi][0], bl[nj][0], acc[mi][nj]);
        acc[mi][nj] = MFMA16(af[mi][1], bl[nj][1], acc[mi][nj]);
      }
    __builtin_amdgcn_s_setprio(0);
    BAR();

    // ---------- phase 2: read B-hi ; stage A(t+1).h1 ----------
    #pragma unroll
    for (int nj = 0; nj < 2; ++nj) {
      bh[nj][0] = *(const bf16x8*)&Bs_[(brow + 32 + nj * 16 + laneq) * 64 + s0];
      bh[nj][1] = *(const bf16x8*)&Bs_[(brow + 32 + nj * 16 + laneq) * 64 + s1];
    }
    if (t + 1 < NT) stage(0, (t + 1) & 1, 1, t + 1);
    BAR();
    __builtin_amdgcn_s_setprio(1);
    #pragma unroll
    for (int mi = 0; mi < 4; ++mi)
      #pragma unroll
      for (int nj = 0; nj < 2; ++nj) {
        acc[mi][2 + nj] = MFMA16(af[mi][0], bh[nj][0], acc[mi][2 + nj]);
        acc[mi][2 + nj] = MFMA16(af[mi][1], bh[nj][1], acc[mi][2 + nj]);
      }
    __builtin_amdgcn_s_setprio(0);
    BAR();

    // ---------- phase 3: read A-hi (overwrite af) ; stage B(t+2).h0 ----------
    #pragma unroll
    for (int mi = 0; mi < 4; ++mi) {
      af[mi][0] = *(const bf16x8*)&As_[(64 + mi * 16 + laneq) * 64 + s0];
      af[mi][1] = *(const bf16x8*)&As_[(64 + mi * 16 + laneq) * 64 + s1];
    }
    if (t + 2 < NT) stage(1, d, 0, t + 2);
    BAR();
    __builtin_amdgcn_s_setprio(1);
    #pragma unroll
    for (int mi = 0; mi < 4; ++mi)
      #pragma unroll
      for (int nj = 0; nj < 2; ++nj) {
        acc[4 + mi][2 + nj] = MFMA16(af[mi][0], bh[nj][0], acc[4 + mi][2 + nj]);
        acc[4 + mi][2 + nj] = MFMA16(af[mi][1], bh[nj][1], acc[4 + mi][2 + nj]);
      }
    __builtin_amdgcn_s_setprio(0);
    BAR();

    // ---------- phase 4: stage B(t+2).h1 ; boundary vmcnt ----------
    if (t + 2 < NT) stage(1, d, 1, t + 2);
    BAR();
    __builtin_amdgcn_s_setprio(1);
    #pragma unroll
    for (int mi = 0; mi < 4; ++mi)
      #pragma unroll
      for (int nj = 0; nj < 2; ++nj) {
        acc[4 + mi][nj] = MFMA16(af[mi][0], bl[nj][0], acc[4 + mi][nj]);
        acc[4 + mi][nj] = MFMA16(af[mi][1], bl[nj][1], acc[4 + mi][nj]);
      }
    __builtin_amdgcn_s_setprio(0);
    if (t == NT - 2)      { WAITVM(0); }
    else if (t < NT - 2)  { WAITVM(4); }
    BAR();
  }

  // ---- epilogue: C = acc + bias ----
  // C/D layout: col = lane&15, row = (lane>>4)*4 + reg
  #pragma unroll
  for (int nj = 0; nj < 4; ++nj) {
    int col = (int)n0 + wn * 64 + nj * 16 + laneq;
    float bv = bias[col];
    #pragma unroll
    for (int mi = 0; mi < 8; ++mi) {
      size_t row = m0 + wm * 128 + mi * 16 + laneh * 4;
      float* cp = C + row * (size_t)N + col;
      #pragma unroll
      for (int r = 0; r < 4; ++r)
        cp[(size_t)r * N] = acc[mi][nj][r] + bv;
    }
  }
}

// ---------- launcher ----------
extern "C" void kernel_launch(void* const* d_in, const int* in_sizes, int n_in,
                              void* d_out, int out_size, void* d_ws, size_t ws_size,
                              hipStream_t stream) {
  const float* x    = (const float*)d_in[0];
  const float* w    = (const float*)d_in[1];
  const float* bias = (const float*)d_in[2];
  float* out = (float*)d_out;

  const long long xN = in_sizes[0];          // M*K
  const long long wN = in_sizes[1];          // N*K
  const int N = in_sizes[2];
  const int K = (int)(wN / N);
  const int M = (int)(xN / K);

  unsigned short* xb = (unsigned short*)d_ws;          // M*K bf16
  unsigned short* wb = xb + xN;                        // N*K bf16

  long long ngroups = xN / 128;
  long long qblocks = (ngroups + 3) / 4;
  quant_x_kernel<<<(int)qblocks, 256, 0, stream>>>(x, xb, ngroups);

  long long cblocks = (wN + 2047) / 2048;
  cvt_w_kernel<<<(int)cblocks, 256, 0, stream>>>(w, wb, wN);

  int grid = (M / BM) * (N / BN);
  gemm256_bias<<<grid, 512, 0, stream>>>(xb, wb, bias, out, M, N, K);
}

// Round 4
// 817.545 us; speedup vs baseline: 1.4534x; 1.0265x over previous
//
#include <hip/hip_runtime.h>
#include <stdint.h>
#include <stddef.h>

// ---------- types ----------
typedef __bf16 bf16x8 __attribute__((ext_vector_type(8)));
typedef float  f32x4  __attribute__((ext_vector_type(4)));

// float -> bf16 bits, round-to-nearest-even (finite inputs)
__device__ __forceinline__ unsigned short f2bf(float f) {
  unsigned int u = __builtin_bit_cast(unsigned int, f);
  u += 0x7fffu + ((u >> 16) & 1u);
  return (unsigned short)(u >> 16);
}

__device__ __forceinline__ void gld_lds16(const void* g, void* l) {
  __builtin_amdgcn_global_load_lds(
      (__attribute__((address_space(1))) void*)(g),
      (__attribute__((address_space(3))) void*)(l), 16, 0, 0);
}

#define BAR()     asm volatile("s_barrier" ::: "memory")
#define WAITVM(n) asm volatile("s_waitcnt vmcnt(" #n ")" ::: "memory")

// ---------- kernel 1: quotient-remainder fake-quant of x, emit bf16 ----------
__global__ __launch_bounds__(256) void quant_x_kernel(
    const float* __restrict__ x, unsigned short* __restrict__ xb, long long ngroups)
{
  const int lane = threadIdx.x & 63;
  const int wv   = threadIdx.x >> 6;
  long long g = (long long)blockIdx.x * 4 + wv;
  if (g >= ngroups) return;

  const float* xg = x + g * 128;
  float2 v = *reinterpret_cast<const float2*>(xg + lane * 2);

  float m = fmaxf(fabsf(v.x), fabsf(v.y));
  #pragma unroll
  for (int off = 32; off; off >>= 1) m = fmaxf(m, __shfl_xor(m, off));
  m = fmaxf(m, 1e-8f);

  float t = m / 7.0f;
  float base = t <= 2.f ? 2.f : t <= 4.f ? 4.f : t <= 8.f ? 8.f
             : t <= 16.f ? 16.f : t <= 32.f ? 32.f : 64.f;
  float inv_base = 1.0f / base;

  float q0 = fminf(fmaxf(rintf(v.x * inv_base), -7.f), 7.f);
  float q1 = fminf(fmaxf(rintf(v.y * inv_base), -7.f), 7.f);
  float r0 = v.x - base * q0;
  float r1 = v.y - base * q1;

  float mr = fmaxf(fabsf(r0), fabsf(r1));
  #pragma unroll
  for (int off = 32; off; off >>= 1) mr = fmaxf(mr, __shfl_xor(mr, off));
  mr = fmaxf(mr, 1e-8f);
  float scale_r = mr / 7.0f;

  float rd0 = fminf(fmaxf(rintf(r0 / scale_r), -8.f), 7.f) * scale_r;
  float rd1 = fminf(fmaxf(rintf(r1 / scale_r), -8.f), 7.f) * scale_r;

  float y0 = base * q0 + rd0;
  float y1 = base * q1 + rd1;

  unsigned int packed = (unsigned int)f2bf(y0) | ((unsigned int)f2bf(y1) << 16);
  *reinterpret_cast<unsigned int*>(xb + g * 128 + lane * 2) = packed;
}

// ---------- kernel 2: fp32 -> bf16 weight conversion ----------
__global__ __launch_bounds__(256) void cvt_w_kernel(
    const float* __restrict__ w, unsigned short* __restrict__ wb, long long n)
{
  long long i = ((long long)blockIdx.x * blockDim.x + threadIdx.x) * 8;
  if (i + 7 >= n) {
    if (i >= n) return;
    for (long long j = i; j < n; ++j) wb[j] = f2bf(w[j]);
    return;
  }
  float4 v0 = *reinterpret_cast<const float4*>(w + i);
  float4 v1 = *reinterpret_cast<const float4*>(w + i + 4);
  uint4 o;
  o.x = (unsigned)f2bf(v0.x) | ((unsigned)f2bf(v0.y) << 16);
  o.y = (unsigned)f2bf(v0.z) | ((unsigned)f2bf(v0.w) << 16);
  o.z = (unsigned)f2bf(v1.x) | ((unsigned)f2bf(v1.y) << 16);
  o.w = (unsigned)f2bf(v1.z) | ((unsigned)f2bf(v1.w) << 16);
  *reinterpret_cast<uint4*>(wb + i) = o;
}

// ---------- kernel 3: 256x256-tile 8-phase bf16 NT-GEMM + bias ----------
// 8 waves (2M x 4N), BK=64, LDS ring = [dbuf][mat][half][128x64] (128 KiB).
// DEEP-PREFETCH schedule: all of tile t+2 staged during tile t:
//   p3: B(t+2).h0 + B(t+2).h1   (B(t) region dead after p2's MFMA lgkm + barrier)
//   p4: A(t+2).h0 + A(t+2).h1   (A(t) region dead after p3's MFMA lgkm + barrier)
// Boundary: vmcnt(8) (exactly the 8 loads issued this tile stay in flight) ->
// every load has 4-6 phases (~600-900 cyc) before anyone waits on it.
// vmcnt(0) only at t == NT-2.
#define BM 256
#define BN 256
#define BK 64

#define MFMA16(a, b, c) __builtin_amdgcn_mfma_f32_16x16x32_bf16(a, b, c, 0, 0, 0)

__global__ __launch_bounds__(512, 2) void gemm256_bias(
    const unsigned short* __restrict__ A,   // [M][K] bf16 bits
    const unsigned short* __restrict__ B,   // [N][K] bf16 bits
    const float* __restrict__ bias,         // [N]
    float* __restrict__ C,                  // [M][N] fp32
    int M, int N, int K)
{
  __shared__ unsigned short lds[2][2][2][128 * 64];   // [dbuf][A/B][half] : 128 KiB

  const int tid  = threadIdx.x;
  const int lane = tid & 63;
  const int wid  = tid >> 6;       // 0..7
  const int wm   = wid >> 2;       // 0..1
  const int wn   = wid & 3;        // 0..3
  const int laneq = lane & 15;
  const int laneh = lane >> 4;
  const int lq7   = laneq & 7;

  // bijective XCD swizzle (grid % 8 == 0 for this shape)
  int nwg = gridDim.x;
  int bid = blockIdx.x;
  int wg = ((nwg & 7) == 0) ? ((bid & 7) * (nwg >> 3) + (bid >> 3)) : bid;

  const int ntn = N / BN;
  const int tm = wg / ntn;
  const int tn = wg % ntn;
  const size_t m0 = (size_t)tm * BM;
  const size_t n0 = (size_t)tn * BN;

  const int NT = K / BK;

  // swizzled 16B-slot offsets (elements) for ks=0,1
  const int s0 = ((0 * 4 + laneh) ^ lq7) * 8;
  const int s1 = ((1 * 4 + laneh) ^ lq7) * 8;

  f32x4 acc[8][4];
  #pragma unroll
  for (int i = 0; i < 8; i++)
    #pragma unroll
    for (int j = 0; j < 4; j++)
      acc[i][j] = (f32x4){0.f, 0.f, 0.f, 0.f};

  // stage one 128x64 half-tile (2 x global_load_lds per thread)
  auto stage = [&](int mat, int d, int h, int kt) {
    const unsigned short* gbase = (mat == 0)
        ? (A + (m0 + (size_t)h * 128) * (size_t)K)
        : (B + (n0 + (size_t)h * 128) * (size_t)K);
    const int k0 = kt * BK;
    #pragma unroll
    for (int l = 0; l < 2; ++l) {
      int c   = l * 512 + tid;          // chunk 0..1023
      int row = c >> 3;                 // 0..127
      int s   = (c & 7) ^ (row & 7);    // inverse-swizzled global slot
      gld_lds16(gbase + (size_t)row * K + k0 + s * 8,
                (char*)&lds[d][mat][h][0] + (l * 512 + wid * 64) * 16);
    }
  };

  // ---- prologue: stage tile0 + tile1 completely; wait only for tile0 ----
  stage(0, 0, 0, 0); stage(0, 0, 1, 0);
  stage(1, 0, 0, 0); stage(1, 0, 1, 0);
  stage(0, 1, 0, 1); stage(0, 1, 1, 1);
  stage(1, 1, 0, 1); stage(1, 1, 1, 1);
  WAITVM(8);          // tile0's 8 loads (oldest) arrived; tile1's may fly
  BAR();

  for (int t = 0; t < NT; ++t) {
    const int d = t & 1;
    const unsigned short* As_ = &lds[d][0][wm][0];
    const unsigned short* Bs_ = &lds[d][1][wn >> 1][0];
    const int brow = (wn & 1) * 64;

    bf16x8 af[4][2], bl[2][2], bh[2][2];

    // ---------- phase 1: read A-lo + B-lo ----------
    #pragma unroll
    for (int mi = 0; mi < 4; ++mi) {
      af[mi][0] = *(const bf16x8*)&As_[(mi * 16 + laneq) * 64 + s0];
      af[mi][1] = *(const bf16x8*)&As_[(mi * 16 + laneq) * 64 + s1];
    }
    #pragma unroll
    for (int nj = 0; nj < 2; ++nj) {
      bl[nj][0] = *(const bf16x8*)&Bs_[(brow + nj * 16 + laneq) * 64 + s0];
      bl[nj][1] = *(const bf16x8*)&Bs_[(brow + nj * 16 + laneq) * 64 + s1];
    }
    BAR();
    __builtin_amdgcn_s_setprio(1);
    #pragma unroll
    for (int mi = 0; mi < 4; ++mi)
      #pragma unroll
      for (int nj = 0; nj < 2; ++nj) {
        acc[mi][nj] = MFMA16(af[mi][0], bl[nj][0], acc[mi][nj]);
        acc[mi][nj] = MFMA16(af[mi][1], bl[nj][1], acc[mi][nj]);
      }
    __builtin_amdgcn_s_setprio(0);
    BAR();

    // ---------- phase 2: read B-hi ----------
    #pragma unroll
    for (int nj = 0; nj < 2; ++nj) {
      bh[nj][0] = *(const bf16x8*)&Bs_[(brow + 32 + nj * 16 + laneq) * 64 + s0];
      bh[nj][1] = *(const bf16x8*)&Bs_[(brow + 32 + nj * 16 + laneq) * 64 + s1];
    }
    BAR();
    __builtin_amdgcn_s_setprio(1);
    #pragma unroll
    for (int mi = 0; mi < 4; ++mi)
      #pragma unroll
      for (int nj = 0; nj < 2; ++nj) {
        acc[mi][2 + nj] = MFMA16(af[mi][0], bh[nj][0], acc[mi][2 + nj]);
        acc[mi][2 + nj] = MFMA16(af[mi][1], bh[nj][1], acc[mi][2 + nj]);
      }
    __builtin_amdgcn_s_setprio(0);
    BAR();

    // ---------- phase 3: read A-hi ; stage B(t+2) both halves ----------
    #pragma unroll
    for (int mi = 0; mi < 4; ++mi) {
      af[mi][0] = *(const bf16x8*)&As_[(64 + mi * 16 + laneq) * 64 + s0];
      af[mi][1] = *(const bf16x8*)&As_[(64 + mi * 16 + laneq) * 64 + s1];
    }
    if (t + 2 < NT) { stage(1, d, 0, t + 2); stage(1, d, 1, t + 2); }
    BAR();
    __builtin_amdgcn_s_setprio(1);
    #pragma unroll
    for (int mi = 0; mi < 4; ++mi)
      #pragma unroll
      for (int nj = 0; nj < 2; ++nj) {
        acc[4 + mi][2 + nj] = MFMA16(af[mi][0], bh[nj][0], acc[4 + mi][2 + nj]);
        acc[4 + mi][2 + nj] = MFMA16(af[mi][1], bh[nj][1], acc[4 + mi][2 + nj]);
      }
    __builtin_amdgcn_s_setprio(0);
    BAR();

    // ---------- phase 4: stage A(t+2) both halves ; boundary vmcnt ----------
    if (t + 2 < NT) { stage(0, d, 0, t + 2); stage(0, d, 1, t + 2); }
    __builtin_amdgcn_s_setprio(1);
    #pragma unroll
    for (int mi = 0; mi < 4; ++mi)
      #pragma unroll
      for (int nj = 0; nj < 2; ++nj) {
        acc[4 + mi][nj] = MFMA16(af[mi][0], bl[nj][0], acc[4 + mi][nj]);
        acc[4 + mi][nj] = MFMA16(af[mi][1], bl[nj][1], acc[4 + mi][nj]);
      }
    __builtin_amdgcn_s_setprio(0);
    if (t == NT - 2)      { WAITVM(0); }
    else if (t < NT - 2)  { WAITVM(8); }
    BAR();
  }

  // ---- epilogue: C = acc + bias ----
  // C/D layout: col = lane&15, row = (lane>>4)*4 + reg
  #pragma unroll
  for (int nj = 0; nj < 4; ++nj) {
    int col = (int)n0 + wn * 64 + nj * 16 + laneq;
    float bv = bias[col];
    #pragma unroll
    for (int mi = 0; mi < 8; ++mi) {
      size_t row = m0 + wm * 128 + mi * 16 + laneh * 4;
      float* cp = C + row * (size_t)N + col;
      #pragma unroll
      for (int r = 0; r < 4; ++r)
        cp[(size_t)r * N] = acc[mi][nj][r] + bv;
    }
  }
}

// ---------- launcher ----------
extern "C" void kernel_launch(void* const* d_in, const int* in_sizes, int n_in,
                              void* d_out, int out_size, void* d_ws, size_t ws_size,
                              hipStream_t stream) {
  const float* x    = (const float*)d_in[0];
  const float* w    = (const float*)d_in[1];
  const float* bias = (const float*)d_in[2];
  float* out = (float*)d_out;

  const long long xN = in_sizes[0];          // M*K
  const long long wN = in_sizes[1];          // N*K
  const int N = in_sizes[2];
  const int K = (int)(wN / N);
  const int M = (int)(xN / K);

  unsigned short* xb = (unsigned short*)d_ws;          // M*K bf16
  unsigned short* wb = xb + xN;                        // N*K bf16

  long long ngroups = xN / 128;
  long long qblocks = (ngroups + 3) / 4;
  quant_x_kernel<<<(int)qblocks, 256, 0, stream>>>(x, xb, ngroups);

  long long cblocks = (wN + 2047) / 2048;
  cvt_w_kernel<<<(int)cblocks, 256, 0, stream>>>(w, wb, wN);

  int grid = (M / BM) * (N / BN);
  gemm256_bias<<<grid, 512, 0, stream>>>(xb, wb, bias, out, M, N, K);
}